// Round 4
// baseline (270.943 us; speedup 1.0000x reference)
//
#include <hip/hip_runtime.h>

// SNN ALIF step, B=32, N=4096, D=8, NE=2048, DE=4.
// Union-row formulation: each active W row is read ONCE (HBM-unique bytes)
// and scattered into per-batch accumulators via a 32-bit batch mask.
// K1: per-row spike/adapt over all batches -> (mask,row) compacted lists.
// K2: 16 col-tiles x 16 row-splits, 8 waves: pipelined float4 row loads,
//     scalar-mask-driven accumulate into 32 batch accs, LDS combine, partials.
// K3: reduce 16 partials + fused membrane update.

#define B_   32
#define N_   4096
#define D_   8
#define NE_  2048
#define DE_  4
#define BN_  (B_ * N_)
#define BNE_ (B_ * NE_)
#define NWAVE 8
#define NSPLIT 16
#define GSTRIDE (NSPLIT * NWAVE)   // 128 global waves over rows

__device__ __forceinline__ float4 ld4(const float* p) { return *(const float4*)p; }
__device__ __forceinline__ void add4(float4& a, const float4 w) {
    a.x += w.x; a.y += w.y; a.z += w.z; a.w += w.w;
}

// ---------------- K1: spikes + per-row batch masks ----------------
// blocks 0..15: internal rows (256 each); blocks 16..23: external rows.
__global__ __launch_bounds__(256) void snn_spike_mask(
    const float* __restrict__ V, const float* __restrict__ a,
    const float* __restrict__ Xd, const float* __restrict__ Xext,
    const float* __restrict__ dmap_int, const float* __restrict__ dmap_ext,
    float* __restrict__ out,
    int* __restrict__ cnt_int, int* __restrict__ cnt_ext,
    uint2* __restrict__ ent_int, uint2* __restrict__ ent_ext)
{
#pragma clang fp contract(off)
    // exact op order for th: a 1-ulp difference can flip a spike (absmax 1.0)
    __shared__ uint2 s_ent[256];
    __shared__ int lc;
    int tid = threadIdx.x;
    if (tid == 0) lc = 0;
    __syncthreads();
    int c = blockIdx.x;
    if (c < 16) {
        int i = c * 256 + tid;
        int di = 0;
        #pragma unroll
        for (int d = 1; d < D_; ++d)
            if (dmap_int[d * N_ + i] != 0.0f) di = d;
        unsigned m = 0;
        #pragma unroll 8
        for (int b = 0; b < B_; ++b) {
            int t = b * N_ + i;
            float av = a[t];
            float vv = V[t];
            float th = 1.0f + 1.8f * av;
            float x = (vv - th >= 0.0f) ? 1.0f : 0.0f;
            out[t] = x;                          // X
            out[2 * BN_ + t] = 0.98f * av + x;   // a_new
            // Xd_new[0]=X, Xd_new[d>=1]=Xd[d-1]
            float xi = (di == 0) ? x : Xd[(size_t)(di - 1) * BN_ + t];
            if (xi != 0.0f) m |= 1u << b;
        }
        if (m) {
            int p = atomicAdd(&lc, 1);           // LDS atomic only
            s_ent[p] = make_uint2(m, (unsigned)i);
        }
        __syncthreads();
        if (tid == 0) cnt_int[c] = lc;
        if (tid < lc) ent_int[c * 256 + tid] = s_ent[tid];
    } else {
        int j = (c - 16) * 256 + tid;
        int de = 0;
        #pragma unroll
        for (int d = 1; d < DE_; ++d)
            if (dmap_ext[d * NE_ + j] != 0.0f) de = d;
        unsigned m = 0;
        #pragma unroll 8
        for (int b = 0; b < B_; ++b) {
            float xe = Xext[(size_t)de * BNE_ + b * NE_ + j];  // no shift for ext
            if (xe != 0.0f) m |= 1u << b;
        }
        if (m) {
            int p = atomicAdd(&lc, 1);
            s_ent[p] = make_uint2(m, (unsigned)j);
        }
        __syncthreads();
        if (tid == 0) cnt_ext[c - 16] = lc;
        if (tid < lc) ent_ext[(c - 16) * 256 + tid] = s_ent[tid];
    }
}

// ---------------- K2: union-row gather-accumulate ----------------
// Process list entries g, g+128, ... with a depth-2 load pipeline.
// mask is forced scalar -> 32-way unrolled s_cbranch chain (avg 1.6 taken).
__device__ __forceinline__ void process_list(
    const float* __restrict__ W, const uint2* sl, int n, int g, int j,
    float4 acc[B_])
{
    int e = g;
    float4 A = make_float4(0.f,0.f,0.f,0.f), Bv = A;
    unsigned mA = 0, mB = 0;
    if (e < n) {
        uint2 t = sl[e];
        mA = __builtin_amdgcn_readfirstlane(t.x);
        A = ld4(W + (size_t)t.y * N_ + j);
    }
    if (e + GSTRIDE < n) {
        uint2 t = sl[e + GSTRIDE];
        mB = __builtin_amdgcn_readfirstlane(t.x);
        Bv = ld4(W + (size_t)t.y * N_ + j);
    }
    for (; e < n; e += GSTRIDE) {
        float4 C = make_float4(0.f,0.f,0.f,0.f);
        unsigned mC = 0;
        if (e + 2 * GSTRIDE < n) {
            uint2 t = sl[e + 2 * GSTRIDE];
            mC = __builtin_amdgcn_readfirstlane(t.x);
            C = ld4(W + (size_t)t.y * N_ + j);
        }
        unsigned m = mA;
        #pragma unroll
        for (int b = 0; b < B_; ++b)
            if (m & (1u << b)) add4(acc[b], A);
        A = Bv; mA = mB; Bv = C; mB = mC;
    }
}

__global__ __launch_bounds__(512, 2) void snn_gather(
    const float* __restrict__ W_int, const float* __restrict__ W_ext,
    const int* __restrict__ cnt_int, const int* __restrict__ cnt_ext,
    const uint2* __restrict__ ent_int, const uint2* __restrict__ ent_ext,
    float* __restrict__ partial)
{
    __shared__ __align__(16) char smem[(N_ + NE_) * 8];   // 48 KB, reused
    uint2* s_ei = (uint2*)smem;
    uint2* s_ee = (uint2*)(smem + (size_t)N_ * 8);
    float4 (*red)[4][64] = (float4 (*)[4][64])smem;       // 32 KB alias (post-use)

    int tid = threadIdx.x;
    int w = __builtin_amdgcn_readfirstlane(tid >> 6);
    int lane = tid & 63;
    int tile = blockIdx.x;    // 0..15 col tiles
    int split = blockIdx.y;   // 0..15 row splits
    int j = tile * 256 + lane * 4;

    // prefix-merge per-chunk segments into contiguous LDS lists
    int oi[17]; oi[0] = 0;
    #pragma unroll
    for (int c = 0; c < 16; ++c) oi[c + 1] = oi[c] + cnt_int[c];
    int oe[9]; oe[0] = 0;
    #pragma unroll
    for (int c = 0; c < 8; ++c) oe[c + 1] = oe[c] + cnt_ext[c];
    int ni = oi[16], ne = oe[8];
    #pragma unroll
    for (int c = 0; c < 16; ++c)
        for (int k = tid; k < oi[c + 1] - oi[c]; k += 512)
            s_ei[oi[c] + k] = ent_int[c * 256 + k];
    #pragma unroll
    for (int c = 0; c < 8; ++c)
        for (int k = tid; k < oe[c + 1] - oe[c]; k += 512)
            s_ee[oe[c] + k] = ent_ext[c * 256 + k];
    __syncthreads();

    float4 acc[B_];
    #pragma unroll
    for (int b = 0; b < B_; ++b) acc[b] = make_float4(0.f,0.f,0.f,0.f);

    int g = split * NWAVE + w;   // global wave id 0..127
    process_list(W_int, s_ei, ni, g, j, acc);
    process_list(W_ext, s_ee, ne, g, j, acc);

    // cross-wave combine (8 waves), 4 batches per chunk; smem reused
    for (int chunk = 0; chunk < 8; ++chunk) {
        __syncthreads();
        #pragma unroll
        for (int b4 = 0; b4 < 4; ++b4) red[w][b4][lane] = acc[chunk * 4 + b4];
        __syncthreads();
        if (tid < 256) {
            int b4 = tid >> 6, l2 = tid & 63;
            float4 s = red[0][b4][l2];
            #pragma unroll
            for (int ww = 1; ww < NWAVE; ++ww) add4(s, red[ww][b4][l2]);
            int b = chunk * 4 + b4;
            *(float4*)(partial + ((size_t)split * B_ + b) * N_ + tile * 256 + l2 * 4) = s;
        }
    }
}

// ---------------- K3: reduce partials + membrane update ----------------
__global__ __launch_bounds__(256) void snn_membrane(
    const float* __restrict__ partial, const float* __restrict__ V,
    float* __restrict__ out)
{
    int cell = blockIdx.x * 256 + threadIdx.x;   // 0..32767 float4 cells
    int b = cell >> 10;                          // N_/4 = 1024 cells per batch
    int col = (cell & 1023) * 4;
    int t = b * N_ + col;
    float4 s = make_float4(0.f,0.f,0.f,0.f);
    #pragma unroll
    for (int sp = 0; sp < NSPLIT; ++sp)
        add4(s, *(const float4*)(partial + ((size_t)sp * B_ + b) * N_ + col));
    float4 v = ld4(V + t);
    float4 x = ld4(out + t);      // X written by K1
    float4 vn;
    vn.x = 0.95f * v.x * (1.0f - x.x) + s.x;
    vn.y = 0.95f * v.y * (1.0f - x.y) + s.y;
    vn.z = 0.95f * v.z * (1.0f - x.z) + s.z;
    vn.w = 0.95f * v.w * (1.0f - x.w) + s.w;
    *(float4*)(out + BN_ + t) = vn;
}

extern "C" void kernel_launch(void* const* d_in, const int* in_sizes, int n_in,
                              void* d_out, int out_size, void* d_ws, size_t ws_size,
                              hipStream_t stream)
{
    const float* V        = (const float*)d_in[0];
    const float* a        = (const float*)d_in[1];
    const float* Xd       = (const float*)d_in[2];
    const float* Xext     = (const float*)d_in[3];
    const float* W_int    = (const float*)d_in[4];
    const float* W_ext    = (const float*)d_in[5];
    const float* dmap_int = (const float*)d_in[6];
    const float* dmap_ext = (const float*)d_in[7];
    float* out = (float*)d_out;

    // ws: cnt_int[16]@0 | cnt_ext[8]@64 | ent_int[4096 uint2]@4096 |
    //     ent_ext[2048 uint2]@36864 | partial[16][32][4096] f32 @65536 (8 MB)
    int*   cnt_int = (int*)d_ws;
    int*   cnt_ext = (int*)((char*)d_ws + 64);
    uint2* ent_int = (uint2*)((char*)d_ws + 4096);
    uint2* ent_ext = (uint2*)((char*)d_ws + 36864);
    float* partial = (float*)((char*)d_ws + 65536);

    snn_spike_mask<<<24, 256, 0, stream>>>(
        V, a, Xd, Xext, dmap_int, dmap_ext, out,
        cnt_int, cnt_ext, ent_int, ent_ext);

    dim3 g2(16, NSPLIT);   // col-tiles x row-splits = 256 blocks (1/CU)
    snn_gather<<<g2, 512, 0, stream>>>(
        W_int, W_ext, cnt_int, cnt_ext, ent_int, ent_ext, partial);

    snn_membrane<<<128, 256, 0, stream>>>(partial, V, out);
}

// Round 5
// 245.154 us; speedup vs baseline: 1.1052x; 1.1052x over previous
//
#include <hip/hip_runtime.h>

// SNN ALIF step, B=32, N=4096, D=8, NE=2048, DE=4.
// Union-row formulation: each active W row is read ONCE (HBM-unique bytes)
// and scattered into per-batch accumulators via a 32-bit batch mask.
// K1: 96 blocks: 64 rows x 4 batch-octets; mask OR via LDS; ballot compaction.
// K2: 16 col-tiles x 16 row-splits, 8 waves: pipelined float4 row loads,
//     scalar-mask branch chain into 32 REGISTER accumulators (all indices
//     compile-time: chunk-combine fully unrolled -> no scratch demotion).
// K3: reduce 16 partials + fused membrane update.

#define B_   32
#define N_   4096
#define D_   8
#define NE_  2048
#define DE_  4
#define BN_  (B_ * N_)
#define BNE_ (B_ * NE_)
#define NWAVE 8
#define NSPLIT 16
#define GSTRIDE (NSPLIT * NWAVE)   // 128 global waves over rows
#define NCHI 64                    // int chunks (64 rows each)
#define NCHE 32                    // ext chunks (64 rows each)

__device__ __forceinline__ float4 ld4(const float* p) { return *(const float4*)p; }
__device__ __forceinline__ void add4(float4& a, const float4 w) {
    a.x += w.x; a.y += w.y; a.z += w.z; a.w += w.w;
}

// ---------------- K1: spikes + per-row batch masks ----------------
// blocks 0..63: internal rows; blocks 64..95: external rows.
// 256 threads = 64 rows x 4 batch-octets.
__global__ __launch_bounds__(256) void snn_spike_mask(
    const float* __restrict__ V, const float* __restrict__ a,
    const float* __restrict__ Xd, const float* __restrict__ Xext,
    const float* __restrict__ dmap_int, const float* __restrict__ dmap_ext,
    float* __restrict__ out,
    int* __restrict__ cnt_int, int* __restrict__ cnt_ext,
    uint2* __restrict__ ent_int, uint2* __restrict__ ent_ext)
{
#pragma clang fp contract(off)
    // exact op order for th: a 1-ulp difference can flip a spike (absmax 1.0)
    __shared__ unsigned s_m[4][64];
    int tid = threadIdx.x;
    int lane = tid & 63;
    int o = tid >> 6;            // batch octet: batches o*8 .. o*8+7
    int c = blockIdx.x;
    if (c < NCHI) {
        int i = c * 64 + lane;
        int di = 0;
        #pragma unroll
        for (int d = 1; d < D_; ++d)
            if (dmap_int[d * N_ + i] != 0.0f) di = d;
        unsigned m = 0;
        #pragma unroll
        for (int bb = 0; bb < 8; ++bb) {
            int b = o * 8 + bb;
            int t = b * N_ + i;
            float av = a[t];
            float vv = V[t];
            float th = 1.0f + 1.8f * av;
            float x = (vv - th >= 0.0f) ? 1.0f : 0.0f;
            out[t] = x;                          // X
            out[2 * BN_ + t] = 0.98f * av + x;   // a_new
            // Xd_new[0]=X, Xd_new[d>=1]=Xd[d-1]
            float xi = (di == 0) ? x : Xd[(size_t)(di - 1) * BN_ + t];
            if (xi != 0.0f) m |= 1u << b;
        }
        s_m[o][lane] = m;
        __syncthreads();
        if (tid < 64) {
            unsigned mm = s_m[0][lane] | s_m[1][lane] | s_m[2][lane] | s_m[3][lane];
            unsigned long long bal = __ballot(mm != 0);
            int pos = __popcll(bal & ((1ull << lane) - 1ull));
            if (mm) ent_int[c * 64 + pos] = make_uint2(mm, (unsigned)i);
            if (lane == 0) cnt_int[c] = (int)__popcll(bal);
        }
    } else {
        int cc = c - NCHI;
        int j = cc * 64 + lane;
        int de = 0;
        #pragma unroll
        for (int d = 1; d < DE_; ++d)
            if (dmap_ext[d * NE_ + j] != 0.0f) de = d;
        unsigned m = 0;
        #pragma unroll
        for (int bb = 0; bb < 8; ++bb) {
            int b = o * 8 + bb;
            float xe = Xext[(size_t)de * BNE_ + b * NE_ + j];  // ext: no shift
            if (xe != 0.0f) m |= 1u << b;
        }
        s_m[o][lane] = m;
        __syncthreads();
        if (tid < 64) {
            unsigned mm = s_m[0][lane] | s_m[1][lane] | s_m[2][lane] | s_m[3][lane];
            unsigned long long bal = __ballot(mm != 0);
            int pos = __popcll(bal & ((1ull << lane) - 1ull));
            if (mm) ent_ext[cc * 64 + pos] = make_uint2(mm, (unsigned)j);
            if (lane == 0) cnt_ext[cc] = (int)__popcll(bal);
        }
    }
}

// ---------------- K2: union-row gather-accumulate ----------------
// Entries g, g+128, ... with a depth-2 load pipeline. mask and row are scalar
// (readfirstlane) -> s_cbranch chain (avg 1.6 taken) into register accs.
__device__ __forceinline__ void process_list(
    const float* __restrict__ W, const uint2* sl, int n, int g, int j,
    float4 acc[B_])
{
    int e = g;
    float4 A = make_float4(0.f,0.f,0.f,0.f), Bv = A;
    unsigned mA = 0, mB = 0;
    if (e < n) {
        uint2 t = sl[e];
        mA = __builtin_amdgcn_readfirstlane(t.x);
        unsigned r = __builtin_amdgcn_readfirstlane(t.y);
        A = ld4(W + (size_t)r * N_ + j);
    }
    if (e + GSTRIDE < n) {
        uint2 t = sl[e + GSTRIDE];
        mB = __builtin_amdgcn_readfirstlane(t.x);
        unsigned r = __builtin_amdgcn_readfirstlane(t.y);
        Bv = ld4(W + (size_t)r * N_ + j);
    }
    for (; e < n; e += GSTRIDE) {
        float4 C = make_float4(0.f,0.f,0.f,0.f);
        unsigned mC = 0;
        if (e + 2 * GSTRIDE < n) {
            uint2 t = sl[e + 2 * GSTRIDE];
            mC = __builtin_amdgcn_readfirstlane(t.x);
            unsigned r = __builtin_amdgcn_readfirstlane(t.y);
            C = ld4(W + (size_t)r * N_ + j);
        }
        unsigned m = mA;
        #pragma unroll
        for (int b = 0; b < B_; ++b)
            if (m & (1u << b)) add4(acc[b], A);
        A = Bv; mA = mB; Bv = C; mB = mC;
    }
}

__global__ __launch_bounds__(512, 2) void snn_gather(
    const float* __restrict__ W_int, const float* __restrict__ W_ext,
    const int* __restrict__ cnt_int, const int* __restrict__ cnt_ext,
    const uint2* __restrict__ ent_int, const uint2* __restrict__ ent_ext,
    float* __restrict__ partial)
{
    __shared__ __align__(16) char smem[(N_ + NE_) * 8];   // 48 KB, reused
    __shared__ int s_oi[NCHI + 1], s_oe[NCHE + 1];
    uint2* s_ei = (uint2*)smem;
    uint2* s_ee = (uint2*)(smem + (size_t)N_ * 8);
    float4 (*red)[4][64] = (float4 (*)[4][64])smem;       // 32 KB alias (post-use)

    int tid = threadIdx.x;
    int w = __builtin_amdgcn_readfirstlane(tid >> 6);
    int lane = tid & 63;
    int tile = blockIdx.x;    // 0..15 col tiles
    int split = blockIdx.y;   // 0..15 row splits
    int j = tile * 256 + lane * 4;

    // prefix offsets (thread 0, serial over 96 counts), then parallel merge copy
    if (tid == 0) {
        int s = 0; s_oi[0] = 0;
        for (int cc = 0; cc < NCHI; ++cc) { s += cnt_int[cc]; s_oi[cc + 1] = s; }
        s = 0; s_oe[0] = 0;
        for (int cc = 0; cc < NCHE; ++cc) { s += cnt_ext[cc]; s_oe[cc + 1] = s; }
    }
    __syncthreads();
    #pragma unroll
    for (int r = 0; r < (NCHI * 64) / 512; ++r) {
        int idx = r * 512 + tid;
        int cc = idx >> 6, slot = idx & 63;
        int base = s_oi[cc];
        if (slot < s_oi[cc + 1] - base) s_ei[base + slot] = ent_int[idx];
    }
    #pragma unroll
    for (int r = 0; r < (NCHE * 64) / 512; ++r) {
        int idx = r * 512 + tid;
        int cc = idx >> 6, slot = idx & 63;
        int base = s_oe[cc];
        if (slot < s_oe[cc + 1] - base) s_ee[base + slot] = ent_ext[idx];
    }
    __syncthreads();
    int ni = s_oi[NCHI], ne = s_oe[NCHE];

    float4 acc[B_];
    #pragma unroll
    for (int b = 0; b < B_; ++b) acc[b] = make_float4(0.f,0.f,0.f,0.f);

    int g = split * NWAVE + w;   // global wave id 0..127
    process_list(W_int, s_ei, ni, g, j, acc);
    process_list(W_ext, s_ee, ne, g, j, acc);

    // cross-wave combine: FULLY UNROLLED so acc[] indices are compile-time
    // constants (dynamic index would demote acc to scratch -> R4 regression)
    #pragma unroll
    for (int chunk = 0; chunk < 8; ++chunk) {
        __syncthreads();
        #pragma unroll
        for (int b4 = 0; b4 < 4; ++b4) red[w][b4][lane] = acc[chunk * 4 + b4];
        __syncthreads();
        if (tid < 256) {
            int b4 = tid >> 6, l2 = tid & 63;
            float4 s = red[0][b4][l2];
            #pragma unroll
            for (int ww = 1; ww < NWAVE; ++ww) add4(s, red[ww][b4][l2]);
            int b = chunk * 4 + b4;
            *(float4*)(partial + ((size_t)split * B_ + b) * N_ + tile * 256 + l2 * 4) = s;
        }
    }
}

// ---------------- K3: reduce partials + membrane update ----------------
__global__ __launch_bounds__(256) void snn_membrane(
    const float* __restrict__ partial, const float* __restrict__ V,
    float* __restrict__ out)
{
    int cell = blockIdx.x * 256 + threadIdx.x;   // 0..32767 float4 cells
    int b = cell >> 10;                          // N_/4 = 1024 cells per batch
    int col = (cell & 1023) * 4;
    int t = b * N_ + col;
    float4 s = make_float4(0.f,0.f,0.f,0.f);
    #pragma unroll
    for (int sp = 0; sp < NSPLIT; ++sp)
        add4(s, *(const float4*)(partial + ((size_t)sp * B_ + b) * N_ + col));
    float4 v = ld4(V + t);
    float4 x = ld4(out + t);      // X written by K1
    float4 vn;
    vn.x = 0.95f * v.x * (1.0f - x.x) + s.x;
    vn.y = 0.95f * v.y * (1.0f - x.y) + s.y;
    vn.z = 0.95f * v.z * (1.0f - x.z) + s.z;
    vn.w = 0.95f * v.w * (1.0f - x.w) + s.w;
    *(float4*)(out + BN_ + t) = vn;
}

extern "C" void kernel_launch(void* const* d_in, const int* in_sizes, int n_in,
                              void* d_out, int out_size, void* d_ws, size_t ws_size,
                              hipStream_t stream)
{
    const float* V        = (const float*)d_in[0];
    const float* a        = (const float*)d_in[1];
    const float* Xd       = (const float*)d_in[2];
    const float* Xext     = (const float*)d_in[3];
    const float* W_int    = (const float*)d_in[4];
    const float* W_ext    = (const float*)d_in[5];
    const float* dmap_int = (const float*)d_in[6];
    const float* dmap_ext = (const float*)d_in[7];
    float* out = (float*)d_out;

    // ws: cnt_int[64]@0 | cnt_ext[32]@256 | ent_int[4096 uint2]@4096 |
    //     ent_ext[2048 uint2]@36864 | partial[16][32][4096] f32 @65536 (8 MB)
    int*   cnt_int = (int*)d_ws;
    int*   cnt_ext = (int*)((char*)d_ws + 256);
    uint2* ent_int = (uint2*)((char*)d_ws + 4096);
    uint2* ent_ext = (uint2*)((char*)d_ws + 36864);
    float* partial = (float*)((char*)d_ws + 65536);

    snn_spike_mask<<<NCHI + NCHE, 256, 0, stream>>>(
        V, a, Xd, Xext, dmap_int, dmap_ext, out,
        cnt_int, cnt_ext, ent_int, ent_ext);

    dim3 g2(16, NSPLIT);   // col-tiles x row-splits = 256 blocks (1/CU)
    snn_gather<<<g2, 512, 0, stream>>>(
        W_int, W_ext, cnt_int, cnt_ext, ent_int, ent_ext, partial);

    snn_membrane<<<128, 256, 0, stream>>>(partial, V, out);
}

// Round 6
// 173.891 us; speedup vs baseline: 1.5581x; 1.4098x over previous
//
#include <hip/hip_runtime.h>

// SNN ALIF step, B=32, N=4096, D=8, NE=2048, DE=4.
// Union-row formulation, HALF-SPLIT: batches 0-15 / 16-31 get separate
// compacted row lists. K2 waves own one half (16 named float4 accumulators --
// NO arrays, so no scratch demotion possible; R4/R5 regressed on acc[] spill).
// K1: 96 blocks: 64 rows x 4 batch-octets; LDS mask-OR; ballot compaction
//     into per-half per-chunk segments, entries packed mask16<<16|row.
// K2: 16 col-tiles x 16 row-splits, 512 thr = 4 entry-groups x 2 halves.
//     Depth-2 pipelined 1KB row loads; scalar octet-skip branches + predicated
//     FMA into acc0..acc15; 4-round hand-unrolled LDS combine -> partials.
// K3: reduce 16 partials + fused membrane update.

#define B_   32
#define N_   4096
#define D_   8
#define NE_  2048
#define DE_  4
#define BN_  (B_ * N_)
#define BNE_ (B_ * NE_)
#define NSPLIT 16
#define NCHI 64                    // int chunks (64 rows each)
#define NCHE 32                    // ext chunks (64 rows each)

__device__ __forceinline__ float4 ld4(const float* p) { return *(const float4*)p; }
__device__ __forceinline__ void add4(float4& a, const float4 w) {
    a.x += w.x; a.y += w.y; a.z += w.z; a.w += w.w;
}

// ---------------- K1: spikes + per-row half-masks ----------------
__global__ __launch_bounds__(256) void snn_spike_mask(
    const float* __restrict__ V, const float* __restrict__ a,
    const float* __restrict__ Xd, const float* __restrict__ Xext,
    const float* __restrict__ dmap_int, const float* __restrict__ dmap_ext,
    float* __restrict__ out,
    int* __restrict__ cnt_int, int* __restrict__ cnt_ext,
    unsigned* __restrict__ ent_int, unsigned* __restrict__ ent_ext)
{
#pragma clang fp contract(off)
    // exact op order for th: a 1-ulp difference can flip a spike (absmax 1.0)
    __shared__ unsigned s_m[4][64];
    int tid = threadIdx.x;
    int lane = tid & 63;
    int o = tid >> 6;            // batch octet: batches o*8 .. o*8+7
    int c = blockIdx.x;
    if (c < NCHI) {
        int i = c * 64 + lane;
        int di = 0;
        #pragma unroll
        for (int d = 1; d < D_; ++d)
            if (dmap_int[d * N_ + i] != 0.0f) di = d;
        unsigned m = 0;
        #pragma unroll
        for (int bb = 0; bb < 8; ++bb) {
            int b = o * 8 + bb;
            int t = b * N_ + i;
            float av = a[t];
            float vv = V[t];
            float th = 1.0f + 1.8f * av;
            float x = (vv - th >= 0.0f) ? 1.0f : 0.0f;
            out[t] = x;                          // X
            out[2 * BN_ + t] = 0.98f * av + x;   // a_new
            // Xd_new[0]=X, Xd_new[d>=1]=Xd[d-1]
            float xi = (di == 0) ? x : Xd[(size_t)(di - 1) * BN_ + t];
            if (xi != 0.0f) m |= 1u << b;
        }
        s_m[o][lane] = m;
        __syncthreads();
        if (tid < 64) {   // wave 0 exactly
            unsigned mm = s_m[0][lane] | s_m[1][lane] | s_m[2][lane] | s_m[3][lane];
            #pragma unroll
            for (int h = 0; h < 2; ++h) {
                unsigned m16 = (mm >> (16 * h)) & 0xffffu;
                unsigned long long bal = __ballot(m16 != 0);
                int pos = __popcll(bal & ((1ull << lane) - 1ull));
                if (m16) ent_int[(h * NCHI + c) * 64 + pos] = (m16 << 16) | (unsigned)i;
                if (lane == 0) cnt_int[h * NCHI + c] = (int)__popcll(bal);
            }
        }
    } else {
        int cc = c - NCHI;
        int j = cc * 64 + lane;
        int de = 0;
        #pragma unroll
        for (int d = 1; d < DE_; ++d)
            if (dmap_ext[d * NE_ + j] != 0.0f) de = d;
        unsigned m = 0;
        #pragma unroll
        for (int bb = 0; bb < 8; ++bb) {
            int b = o * 8 + bb;
            float xe = Xext[(size_t)de * BNE_ + b * NE_ + j];  // ext: no shift
            if (xe != 0.0f) m |= 1u << b;
        }
        s_m[o][lane] = m;
        __syncthreads();
        if (tid < 64) {
            unsigned mm = s_m[0][lane] | s_m[1][lane] | s_m[2][lane] | s_m[3][lane];
            #pragma unroll
            for (int h = 0; h < 2; ++h) {
                unsigned m16 = (mm >> (16 * h)) & 0xffffu;
                unsigned long long bal = __ballot(m16 != 0);
                int pos = __popcll(bal & ((1ull << lane) - 1ull));
                if (m16) ent_ext[(h * NCHE + cc) * 64 + pos] = (m16 << 16) | (unsigned)j;
                if (lane == 0) cnt_ext[h * NCHE + cc] = (int)__popcll(bal);
            }
        }
    }
}

// ---------------- K2: half-split gather-accumulate ----------------
// predicated FMA of 8 batches (octet) into named accumulators
#define PF4(ACC, F, R) { ACC.x += (F)*(R).x; ACC.y += (F)*(R).y; \
                         ACC.z += (F)*(R).z; ACC.w += (F)*(R).w; }
#define OCT_LO(MO, R) { \
    PF4(acc0,(float)((MO)&1u),R)      PF4(acc1,(float)(((MO)>>1)&1u),R) \
    PF4(acc2,(float)(((MO)>>2)&1u),R) PF4(acc3,(float)(((MO)>>3)&1u),R) \
    PF4(acc4,(float)(((MO)>>4)&1u),R) PF4(acc5,(float)(((MO)>>5)&1u),R) \
    PF4(acc6,(float)(((MO)>>6)&1u),R) PF4(acc7,(float)(((MO)>>7)&1u),R) }
#define OCT_HI(MO, R) { \
    PF4(acc8,(float)((MO)&1u),R)       PF4(acc9,(float)(((MO)>>1)&1u),R) \
    PF4(acc10,(float)(((MO)>>2)&1u),R) PF4(acc11,(float)(((MO)>>3)&1u),R) \
    PF4(acc12,(float)(((MO)>>4)&1u),R) PF4(acc13,(float)(((MO)>>5)&1u),R) \
    PF4(acc14,(float)(((MO)>>6)&1u),R) PF4(acc15,(float)(((MO)>>7)&1u),R) }
#define CONSUME(M, R) { \
    unsigned _lo = (M) & 0xffu;        \
    unsigned _hi = ((M) >> 8) & 0xffu; \
    if (_lo) OCT_LO(_lo, R);           \
    if (_hi) OCT_HI(_hi, R); }

__global__ __launch_bounds__(512, 2) void snn_gather(
    const float* __restrict__ W_int, const float* __restrict__ W_ext,
    const int* __restrict__ cnt_int, const int* __restrict__ cnt_ext,
    const unsigned* __restrict__ ent_int, const unsigned* __restrict__ ent_ext,
    float* __restrict__ partial)
{
    __shared__ __align__(16) char smem[49152];   // lists (48KB) / red (32KB alias)
    __shared__ int s_oi[2][NCHI + 1], s_oe[2][NCHE + 1];
    unsigned* s_li0 = (unsigned*)smem;                     // int half 0 (<=4096)
    unsigned* s_li1 = (unsigned*)(smem + 16384);           // int half 1
    unsigned* s_le0 = (unsigned*)(smem + 32768);           // ext half 0 (<=2048)
    unsigned* s_le1 = (unsigned*)(smem + 40960);           // ext half 1
    float4 (*red)[4][64] = (float4 (*)[4][64])smem;        // 32 KB alias, post-use

    int tid = threadIdx.x;
    int w = __builtin_amdgcn_readfirstlane(tid >> 6);  // 0..7
    int lane = tid & 63;
    int h = w & 1;            // batch half
    int g = w >> 1;           // entry group 0..3
    int tile = blockIdx.x;    // 0..15 col tiles
    int split = blockIdx.y;   // 0..15 row splits
    int j = tile * 256 + lane * 4;

    // prefix offsets: 4 threads (one per half x kind), serial over <=64 counts
    if (tid == 0) {
        int s = 0; s_oi[0][0] = 0;
        for (int cc = 0; cc < NCHI; ++cc) { s += cnt_int[cc]; s_oi[0][cc + 1] = s; }
    } else if (tid == 64) {
        int s = 0; s_oi[1][0] = 0;
        for (int cc = 0; cc < NCHI; ++cc) { s += cnt_int[NCHI + cc]; s_oi[1][cc + 1] = s; }
    } else if (tid == 128) {
        int s = 0; s_oe[0][0] = 0;
        for (int cc = 0; cc < NCHE; ++cc) { s += cnt_ext[cc]; s_oe[0][cc + 1] = s; }
    } else if (tid == 192) {
        int s = 0; s_oe[1][0] = 0;
        for (int cc = 0; cc < NCHE; ++cc) { s += cnt_ext[NCHE + cc]; s_oe[1][cc + 1] = s; }
    }
    __syncthreads();

    // merge per-chunk segments into contiguous per-half LDS lists
    #pragma unroll
    for (int rIt = 0; rIt < (2 * NCHI * 64) / 512; ++rIt) {   // 16 iters
        int idx = rIt * 512 + tid;
        int hh = idx >> 12, cc = (idx >> 6) & 63, ss = idx & 63;
        int base = s_oi[hh][cc];
        if (ss < s_oi[hh][cc + 1] - base) {
            unsigned* dst = hh ? s_li1 : s_li0;
            dst[base + ss] = ent_int[idx];
        }
    }
    #pragma unroll
    for (int rIt = 0; rIt < (2 * NCHE * 64) / 512; ++rIt) {   // 8 iters
        int idx = rIt * 512 + tid;
        int hh = idx >> 11, cc = (idx >> 6) & 31, ss = idx & 63;
        int base = s_oe[hh][cc];
        if (ss < s_oe[hh][cc + 1] - base) {
            unsigned* dst = hh ? s_le1 : s_le0;
            dst[base + ss] = ent_ext[idx];
        }
    }
    __syncthreads();

    const unsigned* myInt = h ? s_li1 : s_li0;
    const unsigned* myExt = h ? s_le1 : s_le0;
    int nInt = s_oi[h][NCHI];
    int nExt = s_oe[h][NCHE];
    int e0 = split * 4 + g;   // entry start; global stride 64

    float4 z4 = make_float4(0.f, 0.f, 0.f, 0.f);
    float4 acc0=z4, acc1=z4, acc2=z4,  acc3=z4,  acc4=z4,  acc5=z4,  acc6=z4,  acc7=z4;
    float4 acc8=z4, acc9=z4, acc10=z4, acc11=z4, acc12=z4, acc13=z4, acc14=z4, acc15=z4;

    // depth-2 pipelined accumulation over a half-list (named accs via macros)
    auto proc = [&](const float* __restrict__ W, const unsigned* sl, int n) {
        int e = e0;
        unsigned eA = 0, eB = 0;
        float4 A = z4, Bv = z4;
        if (e < n) {
            eA = sl[e];
            A = ld4(W + (size_t)(eA & 0xffffu) * N_ + j);
        }
        if (e + 64 < n) {
            eB = sl[e + 64];
            Bv = ld4(W + (size_t)(eB & 0xffffu) * N_ + j);
        }
        for (; e < n; e += 64) {
            unsigned eC = 0; float4 C = z4;
            if (e + 128 < n) {
                eC = sl[e + 128];
                C = ld4(W + (size_t)(eC & 0xffffu) * N_ + j);
            }
            unsigned m = __builtin_amdgcn_readfirstlane(eA) >> 16;
            CONSUME(m, A);
            eA = eB; A = Bv; eB = eC; Bv = C;
        }
    };
    proc(W_int, myInt, nInt);
    proc(W_ext, myExt, nExt);

    // 4-round hand-unrolled cross-wave combine (literal acc indices only)
    #define ROUND(RR, A0, A1, A2, A3) { \
        __syncthreads(); \
        red[w][0][lane] = A0; red[w][1][lane] = A1; \
        red[w][2][lane] = A2; red[w][3][lane] = A3; \
        __syncthreads(); \
        int hh = tid >> 8, b4 = (tid >> 6) & 3, l2 = tid & 63; \
        float4 s = red[hh][b4][l2]; \
        add4(s, red[2 + hh][b4][l2]); \
        add4(s, red[4 + hh][b4][l2]); \
        add4(s, red[6 + hh][b4][l2]); \
        int b = hh * 16 + RR * 4 + b4; \
        *(float4*)(partial + ((size_t)split * B_ + b) * N_ + tile * 256 + l2 * 4) = s; }
    ROUND(0, acc0,  acc1,  acc2,  acc3)
    ROUND(1, acc4,  acc5,  acc6,  acc7)
    ROUND(2, acc8,  acc9,  acc10, acc11)
    ROUND(3, acc12, acc13, acc14, acc15)
    #undef ROUND
}

// ---------------- K3: reduce partials + membrane update ----------------
__global__ __launch_bounds__(256) void snn_membrane(
    const float* __restrict__ partial, const float* __restrict__ V,
    float* __restrict__ out)
{
    int cell = blockIdx.x * 256 + threadIdx.x;   // 0..32767 float4 cells
    int b = cell >> 10;                          // N_/4 = 1024 cells per batch
    int col = (cell & 1023) * 4;
    int t = b * N_ + col;
    float4 s = make_float4(0.f, 0.f, 0.f, 0.f);
    #pragma unroll
    for (int sp = 0; sp < NSPLIT; ++sp)
        add4(s, *(const float4*)(partial + ((size_t)sp * B_ + b) * N_ + col));
    float4 v = ld4(V + t);
    float4 x = ld4(out + t);      // X written by K1
    float4 vn;
    vn.x = 0.95f * v.x * (1.0f - x.x) + s.x;
    vn.y = 0.95f * v.y * (1.0f - x.y) + s.y;
    vn.z = 0.95f * v.z * (1.0f - x.z) + s.z;
    vn.w = 0.95f * v.w * (1.0f - x.w) + s.w;
    *(float4*)(out + BN_ + t) = vn;
}

extern "C" void kernel_launch(void* const* d_in, const int* in_sizes, int n_in,
                              void* d_out, int out_size, void* d_ws, size_t ws_size,
                              hipStream_t stream)
{
    const float* V        = (const float*)d_in[0];
    const float* a        = (const float*)d_in[1];
    const float* Xd       = (const float*)d_in[2];
    const float* Xext     = (const float*)d_in[3];
    const float* W_int    = (const float*)d_in[4];
    const float* W_ext    = (const float*)d_in[5];
    const float* dmap_int = (const float*)d_in[6];
    const float* dmap_ext = (const float*)d_in[7];
    float* out = (float*)d_out;

    // ws: cnt_int[2*64]@0 | cnt_ext[2*32]@512 | ent_int[2*64*64 u32]@1024 |
    //     ent_ext[2*32*64 u32]@33792 | partial[16][32][4096] f32 @65536 (8 MB)
    int*      cnt_int = (int*)d_ws;
    int*      cnt_ext = (int*)((char*)d_ws + 512);
    unsigned* ent_int = (unsigned*)((char*)d_ws + 1024);
    unsigned* ent_ext = (unsigned*)((char*)d_ws + 33792);
    float*    partial = (float*)((char*)d_ws + 65536);

    snn_spike_mask<<<NCHI + NCHE, 256, 0, stream>>>(
        V, a, Xd, Xext, dmap_int, dmap_ext, out,
        cnt_int, cnt_ext, ent_int, ent_ext);

    dim3 g2(16, NSPLIT);   // col-tiles x row-splits = 256 blocks (1/CU)
    snn_gather<<<g2, 512, 0, stream>>>(
        W_int, W_ext, cnt_int, cnt_ext, ent_int, ent_ext, partial);

    snn_membrane<<<128, 256, 0, stream>>>(partial, V, out);
}

// Round 7
// 152.204 us; speedup vs baseline: 1.7801x; 1.1425x over previous
//
#include <hip/hip_runtime.h>

// SNN ALIF step, B=32, N=4096, D=8, NE=2048, DE=4.
// Per-batch formulation (one float4 acc/lane -- no mask scatter, no spill):
// K1: 96 blocks (64 int + 32 ext chunks of 64 rows) x 4 batch-octet waves;
//     each wave ballot-compacts its 8 batches' active rows into per-(b,chunk)
//     u16 segments. No atomics, no LDS.
// K2: grid (16 tiles, 32 batches) -- block id = tile+16*b => XCD = tile%8:
//     all 32 batch-blocks of a tile share one XCD's L2, so the 157 MB of
//     row re-reads are L2 hits; HBM fetch ~= 40 MB unique-row bytes.
//     4 waves x depth-8 float4 pipeline over the merged LDS row list;
//     LDS combine; fused membrane epilogue (no K3, no partials).

#define B_   32
#define N_   4096
#define D_   8
#define NE_  2048
#define DE_  4
#define BN_  (B_ * N_)
#define BNE_ (B_ * NE_)
#define NCHI 64                    // int chunks (64 rows each)
#define NCHE 32                    // ext chunks (64 rows each)

__device__ __forceinline__ float4 ld4(const float* p) { return *(const float4*)p; }
__device__ __forceinline__ void add4(float4& a, const float4 w) {
    a.x += w.x; a.y += w.y; a.z += w.z; a.w += w.w;
}

// ---------------- K1: spikes + per-batch ballot compaction ----------------
__global__ __launch_bounds__(256) void snn_spike_compact(
    const float* __restrict__ V, const float* __restrict__ a,
    const float* __restrict__ Xd, const float* __restrict__ Xext,
    const float* __restrict__ dmap_int, const float* __restrict__ dmap_ext,
    float* __restrict__ out,
    int* __restrict__ cnt_int, int* __restrict__ cnt_ext,
    unsigned short* __restrict__ list_int, unsigned short* __restrict__ list_ext)
{
#pragma clang fp contract(off)
    // exact op order for th: a 1-ulp difference can flip a spike (absmax 1.0)
    int tid = threadIdx.x;
    int lane = tid & 63;
    int o = tid >> 6;            // this wave owns batches o*8 .. o*8+7
    int c = blockIdx.x;
    if (c < NCHI) {
        int i = c * 64 + lane;
        int di = 0;
        #pragma unroll
        for (int d = 1; d < D_; ++d)
            if (dmap_int[d * N_ + i] != 0.0f) di = d;
        unsigned m = 0;
        #pragma unroll
        for (int bb = 0; bb < 8; ++bb) {
            int b = o * 8 + bb;
            int t = b * N_ + i;
            float av = a[t];
            float vv = V[t];
            float th = 1.0f + 1.8f * av;
            float x = (vv - th >= 0.0f) ? 1.0f : 0.0f;
            out[t] = x;                          // X
            out[2 * BN_ + t] = 0.98f * av + x;   // a_new
            // Xd_new[0]=X, Xd_new[d>=1]=Xd[d-1]
            float xi = (di == 0) ? x : Xd[(size_t)(di - 1) * BN_ + t];
            if (xi != 0.0f) m |= 1u << bb;
        }
        #pragma unroll
        for (int bb = 0; bb < 8; ++bb) {
            int b = o * 8 + bb;
            unsigned long long bal = __ballot((m >> bb) & 1u);
            int pos = __popcll(bal & ((1ull << lane) - 1ull));
            if ((m >> bb) & 1u) list_int[b * N_ + c * 64 + pos] = (unsigned short)i;
            if (lane == 0) cnt_int[b * NCHI + c] = (int)__popcll(bal);
        }
    } else {
        int cc = c - NCHI;
        int j = cc * 64 + lane;
        int de = 0;
        #pragma unroll
        for (int d = 1; d < DE_; ++d)
            if (dmap_ext[d * NE_ + j] != 0.0f) de = d;
        unsigned m = 0;
        #pragma unroll
        for (int bb = 0; bb < 8; ++bb) {
            int b = o * 8 + bb;
            float xe = Xext[(size_t)de * BNE_ + b * NE_ + j];  // ext: no shift
            if (xe != 0.0f) m |= 1u << bb;
        }
        #pragma unroll
        for (int bb = 0; bb < 8; ++bb) {
            int b = o * 8 + bb;
            unsigned long long bal = __ballot((m >> bb) & 1u);
            int pos = __popcll(bal & ((1ull << lane) - 1ull));
            if ((m >> bb) & 1u) list_ext[b * NE_ + cc * 64 + pos] = (unsigned short)j;
            if (lane == 0) cnt_ext[b * NCHE + cc] = (int)__popcll(bal);
        }
    }
}

// ---------------- K2: per-batch gather-accumulate ----------------
// Accumulate n rows of W (row stride N_) at column j; indices in LDS (sl,
// 16B-aligned). Depth-8 software pipeline: 8-16 float4 loads in flight.
__device__ __forceinline__ void accum_rows(const float* __restrict__ W,
                                           const unsigned short* sl, int n, int j,
                                           float4& acc)
{
    if (n <= 0) return;
    int nf = n & ~7;
    if (nf >= 8) {
        uint4 g = *(const uint4*)(sl);   // 8 indices, LDS
        float4 p0 = ld4(W + (size_t)(g.x & 0xffff) * N_ + j);
        float4 p1 = ld4(W + (size_t)(g.x >> 16)    * N_ + j);
        float4 p2 = ld4(W + (size_t)(g.y & 0xffff) * N_ + j);
        float4 p3 = ld4(W + (size_t)(g.y >> 16)    * N_ + j);
        float4 p4 = ld4(W + (size_t)(g.z & 0xffff) * N_ + j);
        float4 p5 = ld4(W + (size_t)(g.z >> 16)    * N_ + j);
        float4 p6 = ld4(W + (size_t)(g.w & 0xffff) * N_ + j);
        float4 p7 = ld4(W + (size_t)(g.w >> 16)    * N_ + j);
        for (int k = 8; k < nf; k += 8) {
            uint4 g2 = *(const uint4*)(sl + k);
            float4 q0 = ld4(W + (size_t)(g2.x & 0xffff) * N_ + j);
            float4 q1 = ld4(W + (size_t)(g2.x >> 16)    * N_ + j);
            float4 q2 = ld4(W + (size_t)(g2.y & 0xffff) * N_ + j);
            float4 q3 = ld4(W + (size_t)(g2.y >> 16)    * N_ + j);
            float4 q4 = ld4(W + (size_t)(g2.z & 0xffff) * N_ + j);
            float4 q5 = ld4(W + (size_t)(g2.z >> 16)    * N_ + j);
            float4 q6 = ld4(W + (size_t)(g2.w & 0xffff) * N_ + j);
            float4 q7 = ld4(W + (size_t)(g2.w >> 16)    * N_ + j);
            add4(acc, p0); add4(acc, p1); add4(acc, p2); add4(acc, p3);
            add4(acc, p4); add4(acc, p5); add4(acc, p6); add4(acc, p7);
            p0 = q0; p1 = q1; p2 = q2; p3 = q3;
            p4 = q4; p5 = q5; p6 = q6; p7 = q7;
        }
        add4(acc, p0); add4(acc, p1); add4(acc, p2); add4(acc, p3);
        add4(acc, p4); add4(acc, p5); add4(acc, p6); add4(acc, p7);
    }
    for (int k = nf; k < n; ++k) {
        float4 w = ld4(W + (size_t)sl[k] * N_ + j);
        add4(acc, w);
    }
}

__global__ __launch_bounds__(256, 2) void snn_current(
    const float* __restrict__ W_int, const float* __restrict__ W_ext,
    const float* __restrict__ V, float* __restrict__ out,
    const int* __restrict__ cnt_int, const int* __restrict__ cnt_ext,
    const unsigned short* __restrict__ list_int,
    const unsigned short* __restrict__ list_ext)
{
    __shared__ __align__(16) unsigned short s_int[N_];   // 8 KB
    __shared__ __align__(16) unsigned short s_ext[NE_];  // 4 KB
    __shared__ int s_oi[NCHI + 1], s_oe[NCHE + 1];
    __shared__ float4 s_red[4][64];                      // 4 KB

    int tid = threadIdx.x;
    int w = tid >> 6, lane = tid & 63;
    int tile = blockIdx.x;    // 0..15 -> XCD = tile % 8 (id = tile + 16*b)
    int b = blockIdx.y;       // 0..31

    // prefix offsets over this batch's chunk counts (2 serial threads)
    if (tid == 0) {
        int s = 0; s_oi[0] = 0;
        for (int c = 0; c < NCHI; ++c) { s += cnt_int[b * NCHI + c]; s_oi[c + 1] = s; }
    } else if (tid == 64) {
        int s = 0; s_oe[0] = 0;
        for (int c = 0; c < NCHE; ++c) { s += cnt_ext[b * NCHE + c]; s_oe[c + 1] = s; }
    }
    __syncthreads();
    // merge per-chunk segments into contiguous LDS lists
    #pragma unroll
    for (int r = 0; r < (NCHI * 64) / 256; ++r) {    // 16 iters
        int idx = r * 256 + tid;
        int c = idx >> 6, ss = idx & 63;
        int base = s_oi[c];
        if (ss < s_oi[c + 1] - base) s_int[base + ss] = list_int[b * N_ + idx];
    }
    #pragma unroll
    for (int r = 0; r < (NCHE * 64) / 256; ++r) {    // 8 iters
        int idx = r * 256 + tid;
        int c = idx >> 6, ss = idx & 63;
        int base = s_oe[c];
        if (ss < s_oe[c + 1] - base) s_ext[base + ss] = list_ext[b * NE_ + idx];
    }
    __syncthreads();
    int ni = s_oi[NCHI], ne = s_oe[NCHE];

    int j = tile * 256 + lane * 4;
    float4 acc = make_float4(0.f, 0.f, 0.f, 0.f);

    // quarter-split across 4 waves; slice starts 8-aligned (16B uint4 reads)
    int qi = ((ni + 31) >> 5) << 3;
    int si = w * qi;
    accum_rows(W_int, s_int + si, min(ni, si + qi) - si, j, acc);
    int qe = ((ne + 31) >> 5) << 3;
    int se = w * qe;
    accum_rows(W_ext, s_ext + se, min(ne, se + qe) - se, j, acc);

    s_red[w][lane] = acc;
    __syncthreads();
    if (w == 0) {
        float4 a0 = s_red[0][lane], a1 = s_red[1][lane];
        float4 a2 = s_red[2][lane], a3 = s_red[3][lane];
        float4 cur;
        cur.x = (a0.x + a1.x) + (a2.x + a3.x);
        cur.y = (a0.y + a1.y) + (a2.y + a3.y);
        cur.z = (a0.z + a1.z) + (a2.z + a3.z);
        cur.w = (a0.w + a1.w) + (a2.w + a3.w);
        // fused: V_new = ALPHA*V*(1-X) + current
        int t = b * N_ + j;
        float4 v = ld4(V + t);
        float4 x = ld4(out + t);      // X written by K1
        float4 vn;
        vn.x = 0.95f * v.x * (1.0f - x.x) + cur.x;
        vn.y = 0.95f * v.y * (1.0f - x.y) + cur.y;
        vn.z = 0.95f * v.z * (1.0f - x.z) + cur.z;
        vn.w = 0.95f * v.w * (1.0f - x.w) + cur.w;
        *(float4*)(out + BN_ + t) = vn;
    }
}

extern "C" void kernel_launch(void* const* d_in, const int* in_sizes, int n_in,
                              void* d_out, int out_size, void* d_ws, size_t ws_size,
                              hipStream_t stream)
{
    const float* V        = (const float*)d_in[0];
    const float* a        = (const float*)d_in[1];
    const float* Xd       = (const float*)d_in[2];
    const float* Xext     = (const float*)d_in[3];
    const float* W_int    = (const float*)d_in[4];
    const float* W_ext    = (const float*)d_in[5];
    const float* dmap_int = (const float*)d_in[6];
    const float* dmap_ext = (const float*)d_in[7];
    float* out = (float*)d_out;

    // ws: cnt_int[32*64]@0 | cnt_ext[32*32]@8192 | list_int[32*4096 u16]@12288 |
    //     list_ext[32*2048 u16]@274432
    int*            cnt_int  = (int*)d_ws;
    int*            cnt_ext  = (int*)((char*)d_ws + 8192);
    unsigned short* list_int = (unsigned short*)((char*)d_ws + 12288);
    unsigned short* list_ext = (unsigned short*)((char*)d_ws + 274432);

    snn_spike_compact<<<NCHI + NCHE, 256, 0, stream>>>(
        V, a, Xd, Xext, dmap_int, dmap_ext, out,
        cnt_int, cnt_ext, list_int, list_ext);

    dim3 g2(16, B_);   // tile-major: XCD = tile % 8 -> L2 row-segment sharing
    snn_current<<<g2, 256, 0, stream>>>(
        W_int, W_ext, V, out, cnt_int, cnt_ext, list_int, list_ext);
}

// Round 8
// 151.034 us; speedup vs baseline: 1.7939x; 1.0077x over previous
//
#include <hip/hip_runtime.h>

// SNN ALIF step, B=32, N=4096, D=8, NE=2048, DE=4. Per-batch gather.
// K1:  96 chunk-blocks: spikes/adapt + ballot-compacted per-(b,chunk) lists.
// K1b: 32 blocks: merge chunks into one contiguous per-batch list, PERMUTED so
//      K2 wave w's contiguous slice holds rows w, w+4, w+8,... -> all waves of
//      all blocks sweep the same sorted row band together => L2 catches the
//      cross-batch re-reads (per-XCD working set = band, not 9.8 MB).
// K2:  grid (16 tiles, 32 batches), id = tile+16b -> XCD = tile%8 (all 32
//      batch-blocks of a tile share one XCD's L2). Bulk-load list, depth-8
//      float4 pipeline, scalar (readfirstlane) row addressing, LDS combine,
//      fused membrane epilogue.

#define B_   32
#define N_   4096
#define D_   8
#define NE_  2048
#define DE_  4
#define BN_  (B_ * N_)
#define BNE_ (B_ * NE_)
#define NCHI 64                    // int chunks (64 rows each)
#define NCHE 32                    // ext chunks (64 rows each)
#define MI_STRIDE 4096             // merged int list stride (u16) per batch
#define ME_STRIDE 2048             // merged ext list stride (u16) per batch

__device__ __forceinline__ float4 ld4(const float* p) { return *(const float4*)p; }
__device__ __forceinline__ void add4(float4& a, const float4 w) {
    a.x += w.x; a.y += w.y; a.z += w.z; a.w += w.w;
}
// per-wave slice length Q: ceil(n/4) rounded up to 8 (16B uint4 alignment)
__device__ __forceinline__ int qalign(int n) { return (((n + 3) >> 2) + 7) & ~7; }

// ---------------- K1: spikes + per-batch ballot compaction ----------------
__global__ __launch_bounds__(256) void snn_spike_compact(
    const float* __restrict__ V, const float* __restrict__ a,
    const float* __restrict__ Xd, const float* __restrict__ Xext,
    const float* __restrict__ dmap_int, const float* __restrict__ dmap_ext,
    float* __restrict__ out,
    int* __restrict__ cnt_int, int* __restrict__ cnt_ext,
    unsigned short* __restrict__ list_int, unsigned short* __restrict__ list_ext)
{
#pragma clang fp contract(off)
    // exact op order for th: a 1-ulp difference can flip a spike (absmax 1.0)
    int tid = threadIdx.x;
    int lane = tid & 63;
    int o = tid >> 6;            // this wave owns batches o*8 .. o*8+7
    int c = blockIdx.x;
    if (c < NCHI) {
        int i = c * 64 + lane;
        int di = 0;
        #pragma unroll
        for (int d = 1; d < D_; ++d)
            if (dmap_int[d * N_ + i] != 0.0f) di = d;
        unsigned m = 0;
        #pragma unroll
        for (int bb = 0; bb < 8; ++bb) {
            int b = o * 8 + bb;
            int t = b * N_ + i;
            float av = a[t];
            float vv = V[t];
            float th = 1.0f + 1.8f * av;
            float x = (vv - th >= 0.0f) ? 1.0f : 0.0f;
            out[t] = x;                          // X
            out[2 * BN_ + t] = 0.98f * av + x;   // a_new
            // Xd_new[0]=X, Xd_new[d>=1]=Xd[d-1]
            float xi = (di == 0) ? x : Xd[(size_t)(di - 1) * BN_ + t];
            if (xi != 0.0f) m |= 1u << bb;
        }
        #pragma unroll
        for (int bb = 0; bb < 8; ++bb) {
            int b = o * 8 + bb;
            unsigned long long bal = __ballot((m >> bb) & 1u);
            int pos = __popcll(bal & ((1ull << lane) - 1ull));
            if ((m >> bb) & 1u) list_int[b * N_ + c * 64 + pos] = (unsigned short)i;
            if (lane == 0) cnt_int[b * NCHI + c] = (int)__popcll(bal);
        }
    } else {
        int cc = c - NCHI;
        int j = cc * 64 + lane;
        int de = 0;
        #pragma unroll
        for (int d = 1; d < DE_; ++d)
            if (dmap_ext[d * NE_ + j] != 0.0f) de = d;
        unsigned m = 0;
        #pragma unroll
        for (int bb = 0; bb < 8; ++bb) {
            int b = o * 8 + bb;
            float xe = Xext[(size_t)de * BNE_ + b * NE_ + j];  // ext: no shift
            if (xe != 0.0f) m |= 1u << bb;
        }
        #pragma unroll
        for (int bb = 0; bb < 8; ++bb) {
            int b = o * 8 + bb;
            unsigned long long bal = __ballot((m >> bb) & 1u);
            int pos = __popcll(bal & ((1ull << lane) - 1ull));
            if ((m >> bb) & 1u) list_ext[b * NE_ + cc * 64 + pos] = (unsigned short)j;
            if (lane == 0) cnt_ext[b * NCHE + cc] = (int)__popcll(bal);
        }
    }
}

// ---------------- K1b: merge chunk segments + interleave permutation -------
// merged[b][(e&3)*Q + (e>>2)] = orig[e]  => wave w's contiguous slice [wQ,wQ+Q)
// walks rows w, w+4, w+8, ... (band-aligned sweep across all waves/blocks)
__global__ __launch_bounds__(256) void snn_merge(
    const int* __restrict__ cnt_int, const int* __restrict__ cnt_ext,
    const unsigned short* __restrict__ list_int,
    const unsigned short* __restrict__ list_ext,
    unsigned short* __restrict__ mint, unsigned short* __restrict__ mext,
    int* __restrict__ hdr)
{
    __shared__ int s_pi[NCHI + 1], s_pe[NCHE + 1];
    int tid = threadIdx.x, b = blockIdx.x;
    if (tid < NCHI) s_pi[tid + 1] = cnt_int[b * NCHI + tid];
    if (tid >= 64 && tid < 64 + NCHE) s_pe[tid - 63] = cnt_ext[b * NCHE + (tid - 64)];
    __syncthreads();
    if (tid == 0) { s_pi[0] = 0; for (int c = 0; c < NCHI; ++c) s_pi[c + 1] += s_pi[c]; }
    else if (tid == 64) { s_pe[0] = 0; for (int c = 0; c < NCHE; ++c) s_pe[c + 1] += s_pe[c]; }
    __syncthreads();
    int ni = s_pi[NCHI], ne = s_pe[NCHE];
    int Qi = qalign(ni), Qe = qalign(ne);
    for (int e = tid; e < ni; e += 256) {
        int lo = 0, hi = NCHI;
        while (hi - lo > 1) { int mid = (lo + hi) >> 1; if (s_pi[mid] <= e) lo = mid; else hi = mid; }
        unsigned short r = list_int[b * N_ + lo * 64 + (e - s_pi[lo])];
        mint[b * MI_STRIDE + (e & 3) * Qi + (e >> 2)] = r;
    }
    for (int e = tid; e < ne; e += 256) {
        int lo = 0, hi = NCHE;
        while (hi - lo > 1) { int mid = (lo + hi) >> 1; if (s_pe[mid] <= e) lo = mid; else hi = mid; }
        unsigned short r = list_ext[b * NE_ + lo * 64 + (e - s_pe[lo])];
        mext[b * ME_STRIDE + (e & 3) * Qe + (e >> 2)] = r;
    }
    if (tid == 0) { hdr[b * 2] = ni; hdr[b * 2 + 1] = ne; }
}

// ---------------- K2: per-batch gather-accumulate ----------------
// Depth-8 pipeline; indices LDS-broadcast + readfirstlane -> SALU addressing.
__device__ __forceinline__ void accum_rows(const float* __restrict__ W,
                                           const unsigned short* sl, int n, int j,
                                           float4& acc)
{
    if (n <= 0) return;
    int nf = n & ~7;
    if (nf >= 8) {
        uint4 g = *(const uint4*)(sl);
        unsigned gx = __builtin_amdgcn_readfirstlane(g.x);
        unsigned gy = __builtin_amdgcn_readfirstlane(g.y);
        unsigned gz = __builtin_amdgcn_readfirstlane(g.z);
        unsigned gw = __builtin_amdgcn_readfirstlane(g.w);
        float4 p0 = ld4(W + (size_t)(gx & 0xffff) * N_ + j);
        float4 p1 = ld4(W + (size_t)(gx >> 16)    * N_ + j);
        float4 p2 = ld4(W + (size_t)(gy & 0xffff) * N_ + j);
        float4 p3 = ld4(W + (size_t)(gy >> 16)    * N_ + j);
        float4 p4 = ld4(W + (size_t)(gz & 0xffff) * N_ + j);
        float4 p5 = ld4(W + (size_t)(gz >> 16)    * N_ + j);
        float4 p6 = ld4(W + (size_t)(gw & 0xffff) * N_ + j);
        float4 p7 = ld4(W + (size_t)(gw >> 16)    * N_ + j);
        for (int k = 8; k < nf; k += 8) {
            uint4 g2 = *(const uint4*)(sl + k);
            unsigned hx = __builtin_amdgcn_readfirstlane(g2.x);
            unsigned hy = __builtin_amdgcn_readfirstlane(g2.y);
            unsigned hz = __builtin_amdgcn_readfirstlane(g2.z);
            unsigned hw = __builtin_amdgcn_readfirstlane(g2.w);
            float4 q0 = ld4(W + (size_t)(hx & 0xffff) * N_ + j);
            float4 q1 = ld4(W + (size_t)(hx >> 16)    * N_ + j);
            float4 q2 = ld4(W + (size_t)(hy & 0xffff) * N_ + j);
            float4 q3 = ld4(W + (size_t)(hy >> 16)    * N_ + j);
            float4 q4 = ld4(W + (size_t)(hz & 0xffff) * N_ + j);
            float4 q5 = ld4(W + (size_t)(hz >> 16)    * N_ + j);
            float4 q6 = ld4(W + (size_t)(hw & 0xffff) * N_ + j);
            float4 q7 = ld4(W + (size_t)(hw >> 16)    * N_ + j);
            add4(acc, p0); add4(acc, p1); add4(acc, p2); add4(acc, p3);
            add4(acc, p4); add4(acc, p5); add4(acc, p6); add4(acc, p7);
            p0 = q0; p1 = q1; p2 = q2; p3 = q3;
            p4 = q4; p5 = q5; p6 = q6; p7 = q7;
        }
        add4(acc, p0); add4(acc, p1); add4(acc, p2); add4(acc, p3);
        add4(acc, p4); add4(acc, p5); add4(acc, p6); add4(acc, p7);
    }
    for (int k = nf; k < n; ++k) {
        unsigned r = __builtin_amdgcn_readfirstlane((unsigned)sl[k]);
        float4 w = ld4(W + (size_t)r * N_ + j);
        add4(acc, w);
    }
}

__global__ __launch_bounds__(256) void snn_current(
    const float* __restrict__ W_int, const float* __restrict__ W_ext,
    const float* __restrict__ V, float* __restrict__ out,
    const unsigned short* __restrict__ mint,
    const unsigned short* __restrict__ mext,
    const int* __restrict__ hdr)
{
    __shared__ __align__(16) unsigned short s_int[MI_STRIDE];  // 8 KB
    __shared__ __align__(16) unsigned short s_ext[ME_STRIDE];  // 4 KB
    __shared__ float4 s_red[4][64];                            // 4 KB

    int tid = threadIdx.x;
    int w = tid >> 6, lane = tid & 63;
    int tile = blockIdx.x;    // 0..15 -> XCD = tile % 8 (id = tile + 16*b)
    int b = blockIdx.y;       // 0..31

    int ni = hdr[b * 2], ne = hdr[b * 2 + 1];
    int Qi = qalign(ni), Qe = qalign(ne);
    int n4i = (4 * Qi) >> 3;                   // uint4 words to stage
    const uint4* gi = (const uint4*)(mint + b * MI_STRIDE);
    for (int k = tid; k < n4i; k += 256) ((uint4*)s_int)[k] = gi[k];
    int n4e = (4 * Qe) >> 3;
    const uint4* ge = (const uint4*)(mext + b * ME_STRIDE);
    for (int k = tid; k < n4e; k += 256) ((uint4*)s_ext)[k] = ge[k];
    __syncthreads();

    int j = tile * 256 + lane * 4;
    float4 acc = make_float4(0.f, 0.f, 0.f, 0.f);

    int di = ni - w; int nwi = di > 0 ? (di + 3) >> 2 : 0;
    accum_rows(W_int, s_int + w * Qi, nwi, j, acc);
    int de = ne - w; int nwe = de > 0 ? (de + 3) >> 2 : 0;
    accum_rows(W_ext, s_ext + w * Qe, nwe, j, acc);

    s_red[w][lane] = acc;
    __syncthreads();
    if (w == 0) {
        float4 a0 = s_red[0][lane], a1 = s_red[1][lane];
        float4 a2 = s_red[2][lane], a3 = s_red[3][lane];
        float4 cur;
        cur.x = (a0.x + a1.x) + (a2.x + a3.x);
        cur.y = (a0.y + a1.y) + (a2.y + a3.y);
        cur.z = (a0.z + a1.z) + (a2.z + a3.z);
        cur.w = (a0.w + a1.w) + (a2.w + a3.w);
        // fused: V_new = ALPHA*V*(1-X) + current
        int t = b * N_ + j;
        float4 v = ld4(V + t);
        float4 x = ld4(out + t);      // X written by K1
        float4 vn;
        vn.x = 0.95f * v.x * (1.0f - x.x) + cur.x;
        vn.y = 0.95f * v.y * (1.0f - x.y) + cur.y;
        vn.z = 0.95f * v.z * (1.0f - x.z) + cur.z;
        vn.w = 0.95f * v.w * (1.0f - x.w) + cur.w;
        *(float4*)(out + BN_ + t) = vn;
    }
}

extern "C" void kernel_launch(void* const* d_in, const int* in_sizes, int n_in,
                              void* d_out, int out_size, void* d_ws, size_t ws_size,
                              hipStream_t stream)
{
    const float* V        = (const float*)d_in[0];
    const float* a        = (const float*)d_in[1];
    const float* Xd       = (const float*)d_in[2];
    const float* Xext     = (const float*)d_in[3];
    const float* W_int    = (const float*)d_in[4];
    const float* W_ext    = (const float*)d_in[5];
    const float* dmap_int = (const float*)d_in[6];
    const float* dmap_ext = (const float*)d_in[7];
    float* out = (float*)d_out;

    // ws: cnt_int[32*64]@0 | cnt_ext[32*32]@8192 | list_int(segs)@12288 |
    //     list_ext(segs)@274432 | mint@405504 | mext@667648 | hdr@798720
    int*            cnt_int  = (int*)d_ws;
    int*            cnt_ext  = (int*)((char*)d_ws + 8192);
    unsigned short* list_int = (unsigned short*)((char*)d_ws + 12288);
    unsigned short* list_ext = (unsigned short*)((char*)d_ws + 274432);
    unsigned short* mint     = (unsigned short*)((char*)d_ws + 405504);
    unsigned short* mext     = (unsigned short*)((char*)d_ws + 667648);
    int*            hdr      = (int*)((char*)d_ws + 798720);

    snn_spike_compact<<<NCHI + NCHE, 256, 0, stream>>>(
        V, a, Xd, Xext, dmap_int, dmap_ext, out,
        cnt_int, cnt_ext, list_int, list_ext);

    snn_merge<<<B_, 256, 0, stream>>>(
        cnt_int, cnt_ext, list_int, list_ext, mint, mext, hdr);

    dim3 g2(16, B_);   // tile-major: XCD = tile % 8 -> L2 row-segment sharing
    snn_current<<<g2, 256, 0, stream>>>(
        W_int, W_ext, V, out, mint, mext, hdr);
}